// Round 8
// baseline (188.495 us; speedup 1.0000x reference)
//
#include <hip/hip_runtime.h>
#include <hip/hip_bf16.h>
#include <math.h>

#define NN 4096
#define NC 128
#define NH 8
#define NV 16
#define NB 4
#define BD 64   // NB*NV

typedef _Float16 half8 __attribute__((ext_vector_type(8)));
typedef __fp16  fp16x2 __attribute__((ext_vector_type(2)));
typedef float floatx4 __attribute__((ext_vector_type(4)));

__device__ __forceinline__ int get_loc(const int* locp){
    int lr = locp[0];
    return (lr >= 0 && lr <= 100) ? lr : 64;
}
__device__ __forceinline__ float head_scale(const float* rr, int h){
    float ts = tanf(0.78539816339744831f * (1.0f + sinf(rr[h])));
    if (!(ts > 0.f)) ts = (ts == 0.f) ? 1e-20f : 1e20f;
    if (ts > 1e20f) ts = 1e20f;
    return ts;
}
// barrier that drains LDS only — leaves global loads (vmcnt) in flight.
__device__ __forceinline__ void lds_barrier(){
    __asm__ __volatile__("s_waitcnt lgkmcnt(0)\n\ts_barrier" ::: "memory");
}

// ---------------------------------------------------------------------------
// FUSED K1+K2 (unchanged — passed R5-R7): blockIdx.x < 512 -> value MFMA;
// else rowstats row i = blockIdx.x-512.
// ---------------------------------------------------------------------------
__global__ __launch_bounds__(256) void k_prep(const float* __restrict__ dist,
                                              const int* __restrict__ locp,
                                              const float* __restrict__ in,
                                              const float* __restrict__ wgt,
                                              float* __restrict__ Kval,
                                              float* __restrict__ xminp,
                                              _Float16* __restrict__ val_t){
    __shared__ unsigned int hist[4][256];
    __shared__ float cand[1024];
    __shared__ unsigned int cnt, selb_s, basec_s, xminu;

    const int t = threadIdx.x, lane = t & 63, wv = t >> 6;

    if (blockIdx.x < 512){
        // ---------------- value branch: val_t[h][bd][j] = in x wgt --------
        const int idx = blockIdx.x;
        const int b   = idx & 3;
        const int j0  = (idx >> 2) * 32;
        const int kl  = (lane >> 4) * 8;        // k-offset inside a K=32 chunk
        const int v   = lane & 15;

        // B-frags straight from global (wgt is 512 KB -> L2-resident).
        half8 Bf[2][4];
#pragma unroll
        for (int nt = 0; nt < 2; nt++){
            const int h = wv * 2 + nt;
            const float* wp = wgt + ((size_t)h * NC + kl) * NV + v;
#pragma unroll
            for (int kc = 0; kc < 4; kc++)
#pragma unroll
                for (int u = 0; u < 8; u++)
                    Bf[nt][kc][u] = (_Float16)wp[(kc * 32 + u) * NV];
        }

        floatx4 acc[2][2];
#pragma unroll
        for (int a = 0; a < 2; a++)
#pragma unroll
            for (int c = 0; c < 2; c++) acc[a][c] = (floatx4){0.f,0.f,0.f,0.f};

        const float* ip = in + ((size_t)b * NN + j0 + v) * NC + kl;
#pragma unroll
        for (int jm = 0; jm < 2; jm++){
            const float* ipm = ip + jm * 16 * NC;
#pragma unroll
            for (int kc = 0; kc < 4; kc++){
                float4 x0 = *(const float4*)(ipm + kc * 32);
                float4 x1 = *(const float4*)(ipm + kc * 32 + 4);
                const float xs[8] = {x0.x,x0.y,x0.z,x0.w,x1.x,x1.y,x1.z,x1.w};
                union { half8 h8; fp16x2 h2[4]; } hi, lo;
#pragma unroll
                for (int u = 0; u < 4; u++){
                    hi.h2[u] = __builtin_amdgcn_cvt_pkrtz(xs[2*u], xs[2*u+1]);
                    float r0 = xs[2*u]   - (float)hi.h2[u][0];
                    float r1 = xs[2*u+1] - (float)hi.h2[u][1];
                    lo.h2[u] = __builtin_amdgcn_cvt_pkrtz(r0, r1);
                }
#pragma unroll
                for (int nt = 0; nt < 2; nt++){
                    acc[jm][nt] = __builtin_amdgcn_mfma_f32_16x16x32_f16(hi.h8, Bf[nt][kc], acc[jm][nt], 0, 0, 0);
                    acc[jm][nt] = __builtin_amdgcn_mfma_f32_16x16x32_f16(lo.h8, Bf[nt][kc], acc[jm][nt], 0, 0, 0);
                }
            }
        }

        const int jw = (lane >> 4) * 4;
#pragma unroll
        for (int jm = 0; jm < 2; jm++)
#pragma unroll
            for (int nt = 0; nt < 2; nt++){
                const int h   = wv * 2 + nt;
                const int row = h * BD + b * NV + v;
                union { _Float16 hh[4]; uint2 u; } o;
#pragma unroll
                for (int u = 0; u < 4; u++) o.hh[u] = (_Float16)acc[jm][nt][u];
                *(uint2*)&val_t[(size_t)row * NN + j0 + jm * 16 + jw] = o.u;
            }
        return;
    }

    // ---------------- rowstats branch (unchanged algorithm) --------------
    const int i = blockIdx.x - 512;
    const int loc = get_loc(locp);
    const unsigned int rank = (unsigned int)(((long long)loc * (NN - 1)) / 100) + 1u;

    float v[16];
    const float4* rp = (const float4*)(dist + (size_t)i * NN);
#pragma unroll
    for (int k = 0; k < 4; k++){
        float4 x4 = rp[k * 256 + t];
        v[4*k+0] = x4.x; v[4*k+1] = x4.y; v[4*k+2] = x4.z; v[4*k+3] = x4.w;
    }
    for (int k = t; k < 1024; k += 256) ((unsigned int*)hist)[k] = 0;
    if (t == 0){ cnt = 0; selb_s = 255u; basec_s = 0u; xminu = 0xFFFFFFFFu; }
    __syncthreads();

    float lmin = 1e30f;
#pragma unroll
    for (int u = 0; u < 16; u++){
        float x = v[u];
        lmin = fminf(lmin, x);
        int b = (int)(x * 256.0f); b = b < 0 ? 0 : (b > 255 ? 255 : b);
        atomicAdd(&hist[wv][b], 1u);
    }
#pragma unroll
    for (int off = 1; off < 64; off <<= 1) lmin = fminf(lmin, __shfl_xor(lmin, off));
    if (lane == 0) atomicMin(&xminu, __float_as_uint(lmin));
    __syncthreads();

    if (t < 64){
        unsigned int lp[4];
        unsigned int run = 0;
#pragma unroll
        for (int q = 0; q < 4; q++){
            int b = 4 * t + q;
            run += hist[0][b] + hist[1][b] + hist[2][b] + hist[3][b];
            lp[q] = run;
        }
        unsigned int incl = run;
#pragma unroll
        for (int d = 1; d < 64; d <<= 1){
            unsigned int y = __shfl_up(incl, d);
            if (t >= d) incl += y;
        }
        unsigned int excl = incl - run;
        if (excl < rank && rank <= incl){
#pragma unroll
            for (int q = 0; q < 4; q++){
                if (excl + lp[q] >= rank){
                    selb_s  = (unsigned int)(4 * t + q);
                    basec_s = excl + (q ? lp[q-1] : 0u);
                    break;
                }
            }
        }
    }
    __syncthreads();
    const unsigned int sb = selb_s;
    if (t == 0) Kval[i] = ((float)sb + 1.0f) * 0.00390625f;   // fallback, overwritten below
#pragma unroll
    for (int u = 0; u < 16; u++){
        float x = v[u];
        int b = (int)(x * 256.0f); b = b < 0 ? 0 : (b > 255 ? 255 : b);
        if ((unsigned int)b == sb){
            unsigned int idx = atomicAdd(&cnt, 1u);
            if (idx < 1024u) cand[idx] = x;
        }
    }
    __syncthreads();
    const unsigned int n = cnt > 1024u ? 1024u : cnt;
    const unsigned int need = rank - basec_s;
    for (unsigned int c0 = t; c0 < n; c0 += 256){
        float x = cand[c0];
        unsigned int lt = 0, le = 0;
        for (unsigned int k2 = 0; k2 < n; k2++){
            float y = cand[k2];
            lt += (y < x); le += (y <= x);
        }
        if (lt < need && need <= le) Kval[i] = x;
    }
    if (t == 0) xminp[i] = __uint_as_float(xminu);
}

// ---------------------------------------------------------------------------
// K3: 64i x 64bd x 512thr (8 waves), K-split wave re-tile — R7 structure,
// one change: V (B-operand) fragments load DIRECTLY FROM GLOBAL into MFMA
// operands (val_t is f16, 4 MB, L2-resident; each frag is a contiguous 16B
// run).  vtile deleted: LDS instrs/wave/tile 6 -> 3 (W write + 2 A reads),
// LDS pipe ~30us -> ~15us of the 50us kernel.  Cost: val_t L2 traffic
// 256->512 MB (2 waves shared each frag) — far under the 34.5 TB/s L2
// ceiling.  V prefetched one full tile-phase ahead (~600cyc >> L2 ~200cyc).
// wtile swizzle unchanged (R7 measured 0 bank conflicts).
// ---------------------------------------------------------------------------
__global__ __launch_bounds__(512) void k_att(const float* __restrict__ dist,
                                             const float* __restrict__ rr,
                                             const _Float16* __restrict__ val_t,
                                             const float* __restrict__ Kvalp,
                                             const float* __restrict__ xminp,
                                             float* __restrict__ out){
    __shared__ alignas(16) char lds_raw[24576];
    _Float16* wtile = (_Float16*)lds_raw;              // [2][4096] f16 = 16 KB
    float*    mrg   = (float*)lds_raw;                 // 24 KB, reused post-loop

    // XCD remap: h fastest within an XCD -> 8 h-blocks share dist rows in L2.
    const int l    = blockIdx.x;               // 0..511
    const int xcd  = l & 7;
    const int sblk = l >> 3;                   // 0..63
    const int i0   = (xcd * 8 + (sblk >> 3)) * 64;
    const int h    = sblk & 7;

    const int t = threadIdx.x;
    const int lane = t & 63, wv = t >> 6;      // wv 0..7
    const float ts  = head_scale(rr, h);
    const float ts2 = ts * 1.44269504088896f;  // exp(a) = exp2(a*log2e)
    const float nts2 = -ts2;

    // dist staging roles: thread t -> row il (0..63), 8-f16 chunk jq (0..7)
    const int il = t >> 3, jq = t & 7;
    const float kvi  = Kvalp[i0 + il];
    const float txmi = ts2 * xminp[i0 + il];

    const float* dp = dist + (size_t)(i0 + il) * NN + jq * 8;

    // swizzled staging index (f16 units): row*64 + (c8 ^ ((row&7)<<3))
    const int stg = il * 64 + ((jq * 8) ^ ((il & 7) << 3));

    // wave MFMA roles: subtile sub (ih32,bh32), K-half khalf
    const int sub   = wv >> 1;                 // 0..3
    const int khalf = wv & 1;
    const int ih32  = (sub >> 1) * 32;
    const int bh32  = (sub & 1) * 32;
    const int cf    = khalf * 32 + (lane >> 4) * 8;   // k-offset (f16) in 64j tile
    const int cswz  = (lane & 7) << 3;
    const int aoff0 = (ih32 +      (lane & 15)) * 64 + (cf ^ cswz);
    const int aoff1 = (ih32 + 16 + (lane & 15)) * 64 + (cf ^ cswz);

    // V direct-from-global fragment pointers (16B contiguous per lane):
    // row = h*BD + bh32 + (lane&15) (+16), col = tile*64 + cf
    const _Float16* vq0 = val_t + (size_t)(h * BD + bh32 + (lane & 15)) * NN + cf;
    const _Float16* vq1 = vq0 + (size_t)16 * NN;

    half8 ones;
#pragma unroll
    for (int u = 0; u < 8; u++) ones[u] = (_Float16)1.0f;

    floatx4 acc00 = (floatx4){0.f,0.f,0.f,0.f};
    floatx4 acc01 = (floatx4){0.f,0.f,0.f,0.f};
    floatx4 acc10 = (floatx4){0.f,0.f,0.f,0.f};
    floatx4 acc11 = (floatx4){0.f,0.f,0.f,0.f};
    floatx4 accs0 = (floatx4){0.f,0.f,0.f,0.f};
    floatx4 accs1 = (floatx4){0.f,0.f,0.f,0.f};

    float4 Ad0, Ad1, Bd0, Bd1;
    half8  VA0, VA1, VB0, VB1;

#define LOADD(D0, D1) do{                                                    \
        D0 = *(const float4*)dp;                                             \
        D1 = *(const float4*)(dp + 4);  dp += 64; }while(0)

#define LOADV(V0, V1) do{                                                    \
        V0 = *(const half8*)vq0;  vq0 += 64;                                 \
        V1 = *(const half8*)vq1;  vq1 += 64; }while(0)

#define STAGEW(BUF, D0, D1) do{                                              \
        const float dd_[8] = {D0.x,D0.y,D0.z,D0.w,D1.x,D1.y,D1.z,D1.w};      \
        union { half8 h8; fp16x2 h2[4]; } uu_;                               \
        _Pragma("unroll")                                                    \
        for (int u_ = 0; u_ < 4; u_++){                                      \
            float a0_ = fmaf(nts2, dd_[2*u_  ], txmi);                       \
            float a1_ = fmaf(nts2, dd_[2*u_+1], txmi);                       \
            a0_ = (dd_[2*u_  ] <= kvi) ? a0_ : -20000.0f;                    \
            a1_ = (dd_[2*u_+1] <= kvi) ? a1_ : -20000.0f;                    \
            uu_.h2[u_] = __builtin_amdgcn_cvt_pkrtz(                         \
                __builtin_amdgcn_exp2f(a0_), __builtin_amdgcn_exp2f(a1_));   \
        }                                                                    \
        *(half8*)&wtile[(BUF) * 4096 + stg] = uu_.h8; }while(0)

#define MFMA_T(BUF, B0, B1) do{                                              \
        const int bb_ = (BUF) * 4096;                                        \
        half8 a0 = *(const half8*)&wtile[bb_ + aoff0];                       \
        half8 a1 = *(const half8*)&wtile[bb_ + aoff1];                       \
        acc00 = __builtin_amdgcn_mfma_f32_16x16x32_f16(a0, B0, acc00, 0, 0, 0); \
        acc01 = __builtin_amdgcn_mfma_f32_16x16x32_f16(a0, B1, acc01, 0, 0, 0); \
        acc10 = __builtin_amdgcn_mfma_f32_16x16x32_f16(a1, B0, acc10, 0, 0, 0); \
        acc11 = __builtin_amdgcn_mfma_f32_16x16x32_f16(a1, B1, acc11, 0, 0, 0); \
        accs0 = __builtin_amdgcn_mfma_f32_16x16x32_f16(a0, ones, accs0, 0, 0, 0); \
        accs1 = __builtin_amdgcn_mfma_f32_16x16x32_f16(a1, ones, accs1, 0, 0, 0); \
        }while(0)

    // ---- prologue: dist+V for tiles 0,1 in flight; W(tile0) staged
    LOADD(Ad0, Ad1);  LOADV(VA0, VA1);        // tile 0
    LOADD(Bd0, Bd1);  LOADV(VB0, VB1);        // tile 1
    STAGEW(0, Ad0, Ad1);

    // ---- main: tiles (2jp, 2jp+1); dist prefetch 2 ahead, V 1 phase ahead
    for (int jp = 0; jp < 31; jp++){
        LOADD(Ad0, Ad1);                      // dist tile 2jp+2
        lds_barrier();                         // wtile[0] (tile 2jp) visible
        MFMA_T(0, VA0, VA1);                   // tile 2jp
        LOADV(VA0, VA1);                       // V tile 2jp+2
        STAGEW(1, Bd0, Bd1);                   // W tile 2jp+1 -> buf1
        LOADD(Bd0, Bd1);                      // dist tile 2jp+3
        lds_barrier();
        MFMA_T(1, VB0, VB1);                   // tile 2jp+1
        LOADV(VB0, VB1);                       // V tile 2jp+3
        STAGEW(0, Ad0, Ad1);                   // W tile 2jp+2 -> buf0
    }
    // ---- tail: tiles 62, 63
    lds_barrier();
    MFMA_T(0, VA0, VA1);                       // tile 62
    STAGEW(1, Bd0, Bd1);                       // W tile 63
    lds_barrier();
    MFMA_T(1, VB0, VB1);                       // tile 63

#undef LOADD
#undef LOADV
#undef STAGEW
#undef MFMA_T

    // ---- K-half merge: wave wv keeps iq=khalf, ships other half to wv^1.
    lds_barrier();                             // all wtile reads done; LDS free
    {
        floatx4 w0, w1, w2;
        if (khalf == 0){ w0 = acc10; w1 = acc11; w2 = accs1; }
        else           { w0 = acc00; w1 = acc01; w2 = accs0; }
        const int mb = wv * 768 + lane * 12;
        *(floatx4*)&mrg[mb    ] = w0;
        *(floatx4*)&mrg[mb + 4] = w1;
        *(floatx4*)&mrg[mb + 8] = w2;
    }
    lds_barrier();
    {
        const int mb = (wv ^ 1) * 768 + lane * 12;
        floatx4 m0 = *(const floatx4*)&mrg[mb    ];
        floatx4 m1 = *(const floatx4*)&mrg[mb + 4];
        floatx4 m2 = *(const floatx4*)&mrg[mb + 8];
        if (khalf == 0){ acc00 += m0; acc01 += m1; accs0 += m2; }
        else           { acc10 += m0; acc11 += m1; accs1 += m2; }
    }

    // ---- epilogue: rows i = i0+ih32+khalf*16+m0+r4; cols bd = bh32+bq*16+d
    const floatx4 A0 = (khalf == 0) ? acc00 : acc10;
    const floatx4 A1 = (khalf == 0) ? acc01 : acc11;
    const floatx4 S  = (khalf == 0) ? accs0 : accs1;
    const int m0i = (lane >> 4) * 4;
    const int d   = lane & 15;
#pragma unroll
    for (int r4 = 0; r4 < 4; r4++){
        const int i = i0 + ih32 + khalf * 16 + m0i + r4;
        const float inv_s = 1.0f / fmaxf(S[r4], 1e-30f);
#pragma unroll
        for (int bq = 0; bq < 2; bq++){
            const int b = (sub & 1) * 2 + bq;
            float cc = (bq == 0 ? A0[r4] : A1[r4]) * inv_s;
            float g = 0.5f * cc * (1.0f + erff(cc * 0.70710678118654752f));
            out[((size_t)b * NN + i) * (NH * NV) + h * NV + d] = g;
        }
    }
}

// ---------------------------------------------------------------------------
extern "C" void kernel_launch(void* const* d_in, const int* in_sizes, int n_in,
                              void* d_out, int out_size, void* d_ws, size_t ws_size,
                              hipStream_t stream) {
    const float* in   = (const float*)d_in[0]; // (B,N,C) f32
    const float* dist = (const float*)d_in[1]; // (N,N) f32
    const float* r    = (const float*)d_in[2]; // (H,1,1) f32
    const float* wgt  = (const float*)d_in[3]; // (H,C,V) f32
    const int*   loc  = (const int*)d_in[4];   // scalar int
    float* out = (float*)d_out;                // (B,N,H*V) f32

    float* Kval = (float*)d_ws;
    float* xmin = Kval + NN;
    _Float16* val_t = (_Float16*)((char*)d_ws + 2 * (size_t)NN * sizeof(float)); // 4 MB

    k_prep<<<512 + NN, 256, 0, stream>>>(dist, loc, in, wgt, Kval, xmin, val_t);
    k_att<<<512, 512, 0, stream>>>(dist, r, val_t, Kval, xmin, out);
}

// Round 9
// 153.217 us; speedup vs baseline: 1.2302x; 1.2302x over previous
//
#include <hip/hip_runtime.h>
#include <hip/hip_bf16.h>
#include <math.h>

#define NN 4096
#define NC 128
#define NH 8
#define NV 16
#define NB 4
#define BD 64   // NB*NV

typedef _Float16 half8 __attribute__((ext_vector_type(8)));
typedef __fp16  fp16x2 __attribute__((ext_vector_type(2)));
typedef float floatx4 __attribute__((ext_vector_type(4)));

__device__ __forceinline__ int get_loc(const int* locp){
    int lr = locp[0];
    return (lr >= 0 && lr <= 100) ? lr : 64;
}
__device__ __forceinline__ float head_scale(const float* rr, int h){
    float ts = tanf(0.78539816339744831f * (1.0f + sinf(rr[h])));
    if (!(ts > 0.f)) ts = (ts == 0.f) ? 1e-20f : 1e20f;
    if (ts > 1e20f) ts = 1e20f;
    return ts;
}
// barrier that drains LDS only — leaves global loads (vmcnt) in flight.
__device__ __forceinline__ void lds_barrier(){
    __asm__ __volatile__("s_waitcnt lgkmcnt(0)\n\ts_barrier" ::: "memory");
}

// ---------------------------------------------------------------------------
// FUSED K1+K2 (unchanged — passed R5-R8): blockIdx.x < 512 -> value MFMA;
// else rowstats row i = blockIdx.x-512.
// ---------------------------------------------------------------------------
__global__ __launch_bounds__(256) void k_prep(const float* __restrict__ dist,
                                              const int* __restrict__ locp,
                                              const float* __restrict__ in,
                                              const float* __restrict__ wgt,
                                              float* __restrict__ Kval,
                                              float* __restrict__ xminp,
                                              _Float16* __restrict__ val_t){
    __shared__ unsigned int hist[4][256];
    __shared__ float cand[1024];
    __shared__ unsigned int cnt, selb_s, basec_s, xminu;

    const int t = threadIdx.x, lane = t & 63, wv = t >> 6;

    if (blockIdx.x < 512){
        // ---------------- value branch: val_t[h][bd][j] = in x wgt --------
        const int idx = blockIdx.x;
        const int b   = idx & 3;
        const int j0  = (idx >> 2) * 32;
        const int kl  = (lane >> 4) * 8;        // k-offset inside a K=32 chunk
        const int v   = lane & 15;

        // B-frags straight from global (wgt is 512 KB -> L2-resident).
        half8 Bf[2][4];
#pragma unroll
        for (int nt = 0; nt < 2; nt++){
            const int h = wv * 2 + nt;
            const float* wp = wgt + ((size_t)h * NC + kl) * NV + v;
#pragma unroll
            for (int kc = 0; kc < 4; kc++)
#pragma unroll
                for (int u = 0; u < 8; u++)
                    Bf[nt][kc][u] = (_Float16)wp[(kc * 32 + u) * NV];
        }

        floatx4 acc[2][2];
#pragma unroll
        for (int a = 0; a < 2; a++)
#pragma unroll
            for (int c = 0; c < 2; c++) acc[a][c] = (floatx4){0.f,0.f,0.f,0.f};

        const float* ip = in + ((size_t)b * NN + j0 + v) * NC + kl;
#pragma unroll
        for (int jm = 0; jm < 2; jm++){
            const float* ipm = ip + jm * 16 * NC;
#pragma unroll
            for (int kc = 0; kc < 4; kc++){
                float4 x0 = *(const float4*)(ipm + kc * 32);
                float4 x1 = *(const float4*)(ipm + kc * 32 + 4);
                const float xs[8] = {x0.x,x0.y,x0.z,x0.w,x1.x,x1.y,x1.z,x1.w};
                union { half8 h8; fp16x2 h2[4]; } hi, lo;
#pragma unroll
                for (int u = 0; u < 4; u++){
                    hi.h2[u] = __builtin_amdgcn_cvt_pkrtz(xs[2*u], xs[2*u+1]);
                    float r0 = xs[2*u]   - (float)hi.h2[u][0];
                    float r1 = xs[2*u+1] - (float)hi.h2[u][1];
                    lo.h2[u] = __builtin_amdgcn_cvt_pkrtz(r0, r1);
                }
#pragma unroll
                for (int nt = 0; nt < 2; nt++){
                    acc[jm][nt] = __builtin_amdgcn_mfma_f32_16x16x32_f16(hi.h8, Bf[nt][kc], acc[jm][nt], 0, 0, 0);
                    acc[jm][nt] = __builtin_amdgcn_mfma_f32_16x16x32_f16(lo.h8, Bf[nt][kc], acc[jm][nt], 0, 0, 0);
                }
            }
        }

        const int jw = (lane >> 4) * 4;
#pragma unroll
        for (int jm = 0; jm < 2; jm++)
#pragma unroll
            for (int nt = 0; nt < 2; nt++){
                const int h   = wv * 2 + nt;
                const int row = h * BD + b * NV + v;
                union { _Float16 hh[4]; uint2 u; } o;
#pragma unroll
                for (int u = 0; u < 4; u++) o.hh[u] = (_Float16)acc[jm][nt][u];
                *(uint2*)&val_t[(size_t)row * NN + j0 + jm * 16 + jw] = o.u;
            }
        return;
    }

    // ---------------- rowstats branch (unchanged algorithm) --------------
    const int i = blockIdx.x - 512;
    const int loc = get_loc(locp);
    const unsigned int rank = (unsigned int)(((long long)loc * (NN - 1)) / 100) + 1u;

    float v[16];
    const float4* rp = (const float4*)(dist + (size_t)i * NN);
#pragma unroll
    for (int k = 0; k < 4; k++){
        float4 x4 = rp[k * 256 + t];
        v[4*k+0] = x4.x; v[4*k+1] = x4.y; v[4*k+2] = x4.z; v[4*k+3] = x4.w;
    }
    for (int k = t; k < 1024; k += 256) ((unsigned int*)hist)[k] = 0;
    if (t == 0){ cnt = 0; selb_s = 255u; basec_s = 0u; xminu = 0xFFFFFFFFu; }
    __syncthreads();

    float lmin = 1e30f;
#pragma unroll
    for (int u = 0; u < 16; u++){
        float x = v[u];
        lmin = fminf(lmin, x);
        int b = (int)(x * 256.0f); b = b < 0 ? 0 : (b > 255 ? 255 : b);
        atomicAdd(&hist[wv][b], 1u);
    }
#pragma unroll
    for (int off = 1; off < 64; off <<= 1) lmin = fminf(lmin, __shfl_xor(lmin, off));
    if (lane == 0) atomicMin(&xminu, __float_as_uint(lmin));
    __syncthreads();

    if (t < 64){
        unsigned int lp[4];
        unsigned int run = 0;
#pragma unroll
        for (int q = 0; q < 4; q++){
            int b = 4 * t + q;
            run += hist[0][b] + hist[1][b] + hist[2][b] + hist[3][b];
            lp[q] = run;
        }
        unsigned int incl = run;
#pragma unroll
        for (int d = 1; d < 64; d <<= 1){
            unsigned int y = __shfl_up(incl, d);
            if (t >= d) incl += y;
        }
        unsigned int excl = incl - run;
        if (excl < rank && rank <= incl){
#pragma unroll
            for (int q = 0; q < 4; q++){
                if (excl + lp[q] >= rank){
                    selb_s  = (unsigned int)(4 * t + q);
                    basec_s = excl + (q ? lp[q-1] : 0u);
                    break;
                }
            }
        }
    }
    __syncthreads();
    const unsigned int sb = selb_s;
    if (t == 0) Kval[i] = ((float)sb + 1.0f) * 0.00390625f;   // fallback, overwritten below
#pragma unroll
    for (int u = 0; u < 16; u++){
        float x = v[u];
        int b = (int)(x * 256.0f); b = b < 0 ? 0 : (b > 255 ? 255 : b);
        if ((unsigned int)b == sb){
            unsigned int idx = atomicAdd(&cnt, 1u);
            if (idx < 1024u) cand[idx] = x;
        }
    }
    __syncthreads();
    const unsigned int n = cnt > 1024u ? 1024u : cnt;
    const unsigned int need = rank - basec_s;
    for (unsigned int c0 = t; c0 < n; c0 += 256){
        float x = cand[c0];
        unsigned int lt = 0, le = 0;
        for (unsigned int k2 = 0; k2 < n; k2++){
            float y = cand[k2];
            lt += (y < x); le += (y <= x);
        }
        if (lt < need && need <= le) Kval[i] = x;
    }
    if (t == 0) xminp[i] = __uint_as_float(xminu);
}

// ---------------------------------------------------------------------------
// K3: 64i x 64bd x 512thr, K-split wave re-tile, swizzled LDS (R7 = 50us,
// 0 bank conflicts).  R8's global-V experiment REVERTED (16-row-scattered
// lane pattern was VMEM-latency-bound: 90us).  This round: scheduling only
// (arithmetic bit-identical to R7):
//  (1) 4-buffer pipeline, ONE barrier per 2 tiles (64 -> 33 barriers):
//      read buffer pair P while staging pair Q; pairing resolves the
//      write-after-read hazard that forced per-tile fences.
//  (2) s_setprio(1) around the MFMA cluster (2 independent blocks/CU at
//      shifted phases -> priority favors the MFMA-phase block).
// ---------------------------------------------------------------------------
__global__ __launch_bounds__(512) void k_att(const float* __restrict__ dist,
                                             const float* __restrict__ rr,
                                             const _Float16* __restrict__ val_t,
                                             const float* __restrict__ Kvalp,
                                             const float* __restrict__ xminp,
                                             float* __restrict__ out){
    __shared__ alignas(16) char lds_raw[65536];
    _Float16* wtile = (_Float16*)lds_raw;              // [4][4096] f16 = 32 KB
    _Float16* vtile = (_Float16*)(lds_raw + 32768);    // [4][4096] f16 = 32 KB
    float*    mrg   = (float*)lds_raw;                 // 24 KB, reused post-loop

    // XCD remap: h fastest within an XCD -> 8 h-blocks share dist rows in L2.
    const int l    = blockIdx.x;               // 0..511
    const int xcd  = l & 7;
    const int sblk = l >> 3;                   // 0..63
    const int i0   = (xcd * 8 + (sblk >> 3)) * 64;
    const int h    = sblk & 7;

    const int t = threadIdx.x;
    const int lane = t & 63, wv = t >> 6;      // wv 0..7
    const float ts  = head_scale(rr, h);
    const float ts2 = ts * 1.44269504088896f;  // exp(a) = exp2(a*log2e)
    const float nts2 = -ts2;

    // staging roles: thread t -> row il (0..63), 8-f16 chunk jq (0..7)
    const int il = t >> 3, jq = t & 7;
    const float kvi  = Kvalp[i0 + il];
    const float txmi = ts2 * xminp[i0 + il];

    const float* dp = dist + (size_t)(i0 + il) * NN + jq * 8;
    const _Float16* vp = val_t + (size_t)(h * BD + il) * NN + jq * 8;

    // swizzled staging index (f16 units): row*64 + (c8 ^ ((row&7)<<3))
    const int stg = il * 64 + ((jq * 8) ^ ((il & 7) << 3));

    // wave MFMA roles: subtile sub (ih32,bh32), K-half khalf
    const int sub   = wv >> 1;                 // 0..3
    const int khalf = wv & 1;
    const int ih32  = (sub >> 1) * 32;
    const int bh32  = (sub & 1) * 32;
    const int cf    = khalf * 32 + (lane >> 4) * 8;   // k-offset (f16) in 64j tile
    const int cswz  = (lane & 7) << 3;
    const int aoff0 = (ih32 +      (lane & 15)) * 64 + (cf ^ cswz);
    const int aoff1 = (ih32 + 16 + (lane & 15)) * 64 + (cf ^ cswz);
    const int boff0 = (bh32 +      (lane & 15)) * 64 + (cf ^ cswz);
    const int boff1 = (bh32 + 16 + (lane & 15)) * 64 + (cf ^ cswz);

    half8 ones;
#pragma unroll
    for (int u = 0; u < 8; u++) ones[u] = (_Float16)1.0f;

    floatx4 acc00 = (floatx4){0.f,0.f,0.f,0.f};
    floatx4 acc01 = (floatx4){0.f,0.f,0.f,0.f};
    floatx4 acc10 = (floatx4){0.f,0.f,0.f,0.f};
    floatx4 acc11 = (floatx4){0.f,0.f,0.f,0.f};
    floatx4 accs0 = (floatx4){0.f,0.f,0.f,0.f};
    floatx4 accs1 = (floatx4){0.f,0.f,0.f,0.f};

    uint4  Av, Bv;
    float4 Ad0, Ad1, Bd0, Bd1;

#define LOADSET(V, D0, D1) do{                                               \
        V  = *(const uint4*)vp;  vp += 64;                                   \
        D0 = *(const float4*)dp;                                             \
        D1 = *(const float4*)(dp + 4);  dp += 64; }while(0)

#define STAGE(BUF, V, D0, D1) do{                                            \
        *(uint4*)&vtile[(BUF) * 4096 + stg] = V;                             \
        const float dd_[8] = {D0.x,D0.y,D0.z,D0.w,D1.x,D1.y,D1.z,D1.w};      \
        union { half8 h8; fp16x2 h2[4]; } uu_;                               \
        _Pragma("unroll")                                                    \
        for (int u_ = 0; u_ < 4; u_++){                                      \
            float a0_ = fmaf(nts2, dd_[2*u_  ], txmi);                       \
            float a1_ = fmaf(nts2, dd_[2*u_+1], txmi);                       \
            a0_ = (dd_[2*u_  ] <= kvi) ? a0_ : -20000.0f;                    \
            a1_ = (dd_[2*u_+1] <= kvi) ? a1_ : -20000.0f;                    \
            uu_.h2[u_] = __builtin_amdgcn_cvt_pkrtz(                         \
                __builtin_amdgcn_exp2f(a0_), __builtin_amdgcn_exp2f(a1_));   \
        }                                                                    \
        *(half8*)&wtile[(BUF) * 4096 + stg] = uu_.h8; }while(0)

#define MFMA_T(BUF) do{                                                      \
        const int bb_ = (BUF) * 4096;                                        \
        half8 a0 = *(const half8*)&wtile[bb_ + aoff0];                       \
        half8 a1 = *(const half8*)&wtile[bb_ + aoff1];                       \
        half8 b0 = *(const half8*)&vtile[bb_ + boff0];                       \
        half8 b1 = *(const half8*)&vtile[bb_ + boff1];                       \
        acc00 = __builtin_amdgcn_mfma_f32_16x16x32_f16(a0, b0, acc00, 0, 0, 0); \
        acc01 = __builtin_amdgcn_mfma_f32_16x16x32_f16(a0, b1, acc01, 0, 0, 0); \
        acc10 = __builtin_amdgcn_mfma_f32_16x16x32_f16(a1, b0, acc10, 0, 0, 0); \
        acc11 = __builtin_amdgcn_mfma_f32_16x16x32_f16(a1, b1, acc11, 0, 0, 0); \
        accs0 = __builtin_amdgcn_mfma_f32_16x16x32_f16(a0, ones, accs0, 0, 0, 0); \
        accs1 = __builtin_amdgcn_mfma_f32_16x16x32_f16(a1, ones, accs1, 0, 0, 0); \
        }while(0)

    // ---- prologue: stage tiles 0,1 into bufs 0,1; tiles 2,3 in registers
    LOADSET(Av, Ad0, Ad1);                     // tile 0
    LOADSET(Bv, Bd0, Bd1);                     // tile 1
    STAGE(0, Av, Ad0, Ad1);
    STAGE(1, Bv, Bd0, Bd1);
    LOADSET(Av, Ad0, Ad1);                     // tile 2
    LOADSET(Bv, Bd0, Bd1);                     // tile 3

    // ---- main: region jp consumes tiles (2jp,2jp+1) from pair P, stages
    // (2jp+2,2jp+3) into pair Q, loads (2jp+4,2jp+5).  ONE barrier/region.
    for (int jp = 0; jp < 31; jp++){
        const int pb = (jp & 1) << 1;          // P = {pb, pb+1}
        const int qb = pb ^ 2;                 // Q = {qb, qb+1}
        lds_barrier();                         // publishes P; Q free; vmcnt in flight
        __builtin_amdgcn_s_setprio(1);
        MFMA_T(pb);                            // tile 2jp
        MFMA_T(pb + 1);                        // tile 2jp+1
        __builtin_amdgcn_s_setprio(0);
        STAGE(qb,     Av, Ad0, Ad1);           // tile 2jp+2
        STAGE(qb + 1, Bv, Bd0, Bd1);           // tile 2jp+3
        if (jp != 30){
            LOADSET(Av, Ad0, Ad1);             // tile 2jp+4
            LOADSET(Bv, Bd0, Bd1);             // tile 2jp+5
        }
    }
    // ---- tail: tiles 62,63 sit in bufs 2,3 (jp=30 staged into Q={2,3})
    lds_barrier();
    MFMA_T(2);
    MFMA_T(3);

#undef LOADSET
#undef STAGE
#undef MFMA_T

    // ---- K-half merge: wave wv keeps iq=khalf, ships other half to wv^1.
    lds_barrier();                             // all tile reads done; LDS free
    {
        floatx4 w0, w1, w2;
        if (khalf == 0){ w0 = acc10; w1 = acc11; w2 = accs1; }
        else           { w0 = acc00; w1 = acc01; w2 = accs0; }
        const int mb = wv * 768 + lane * 12;
        *(floatx4*)&mrg[mb    ] = w0;
        *(floatx4*)&mrg[mb + 4] = w1;
        *(floatx4*)&mrg[mb + 8] = w2;
    }
    lds_barrier();
    {
        const int mb = (wv ^ 1) * 768 + lane * 12;
        floatx4 m0 = *(const floatx4*)&mrg[mb    ];
        floatx4 m1 = *(const floatx4*)&mrg[mb + 4];
        floatx4 m2 = *(const floatx4*)&mrg[mb + 8];
        if (khalf == 0){ acc00 += m0; acc01 += m1; accs0 += m2; }
        else           { acc10 += m0; acc11 += m1; accs1 += m2; }
    }

    // ---- epilogue: rows i = i0+ih32+khalf*16+m0+r4; cols bd = bh32+bq*16+d
    const floatx4 A0 = (khalf == 0) ? acc00 : acc10;
    const floatx4 A1 = (khalf == 0) ? acc01 : acc11;
    const floatx4 S  = (khalf == 0) ? accs0 : accs1;
    const int m0i = (lane >> 4) * 4;
    const int d   = lane & 15;
#pragma unroll
    for (int r4 = 0; r4 < 4; r4++){
        const int i = i0 + ih32 + khalf * 16 + m0i + r4;
        const float inv_s = 1.0f / fmaxf(S[r4], 1e-30f);
#pragma unroll
        for (int bq = 0; bq < 2; bq++){
            const int b = (sub & 1) * 2 + bq;
            float cc = (bq == 0 ? A0[r4] : A1[r4]) * inv_s;
            float g = 0.5f * cc * (1.0f + erff(cc * 0.70710678118654752f));
            out[((size_t)b * NN + i) * (NH * NV) + h * NV + d] = g;
        }
    }
}

// ---------------------------------------------------------------------------
extern "C" void kernel_launch(void* const* d_in, const int* in_sizes, int n_in,
                              void* d_out, int out_size, void* d_ws, size_t ws_size,
                              hipStream_t stream) {
    const float* in   = (const float*)d_in[0]; // (B,N,C) f32
    const float* dist = (const float*)d_in[1]; // (N,N) f32
    const float* r    = (const float*)d_in[2]; // (H,1,1) f32
    const float* wgt  = (const float*)d_in[3]; // (H,C,V) f32
    const int*   loc  = (const int*)d_in[4];   // scalar int
    float* out = (float*)d_out;                // (B,N,H*V) f32

    float* Kval = (float*)d_ws;
    float* xmin = Kval + NN;
    _Float16* val_t = (_Float16*)((char*)d_ws + 2 * (size_t)NN * sizeof(float)); // 4 MB

    k_prep<<<512 + NN, 256, 0, stream>>>(dist, loc, in, wgt, Kval, xmin, val_t);
    k_att<<<512, 512, 0, stream>>>(dist, r, val_t, Kval, xmin, out);
}